// Round 2
// baseline (685.643 us; speedup 1.0000x reference)
//
#include <hip/hip_runtime.h>
#include <hip/hip_bf16.h>

// Performer fast-attention, bf16-MFMA pipeline:
//  1. prep_x(K):  K fp32 -> Kb bf16, cX[row] = -0.5*||x||^2 - 0.5*ln(512)
//  2. prep_omega: omega fp32 -> bf16 (omega rows are already B^T layout)
//  3. phi(K):     K_hat^T bf16 [512][65536]  (transposed store from fragments)
//  4. rowsum:     k_ones[feat] = sum_n K_hat[n][feat]
//  5. prep_VT:    V fp32 -> V^T bf16 [512][n]
//  6. kv GEMM:    split-K (32) NT GEMM -> fp32 partials (aliased into d_out)
//  7. prep_x(Q) -> Qb
//  8. phi(Q):     Q_hat bf16 [65536][512] row-major
//  9. reduce_kv:  sum partials -> kvT bf16 [512][512]  (kv^T = B^T for final)
// 10. d_diag:     Q_hat @ k_ones
// 11. final GEMM: out = (Q_hat @ kv) / d_diag

typedef __bf16 bf16x8 __attribute__((ext_vector_type(8)));
typedef float f32x4 __attribute__((ext_vector_type(4)));
typedef unsigned short ushort_t;
typedef ushort_t u16x8 __attribute__((ext_vector_type(8)));
typedef ushort_t u16x4 __attribute__((ext_vector_type(4)));

#define N_NODES 65536
#define FEAT 512

__device__ __forceinline__ ushort_t f2b(float f) {
  unsigned u = __builtin_bit_cast(unsigned, f);
  unsigned r = (u + 0x7fffu + ((u >> 16) & 1u)) >> 16;
  return (ushort_t)r;
}
__device__ __forceinline__ float b2f(ushort_t u) {
  return __builtin_bit_cast(float, ((unsigned)u) << 16);
}

__device__ __forceinline__ void load16(const ushort_t* g, ushort_t* l) {
  __builtin_amdgcn_global_load_lds((const __attribute__((address_space(1))) void*)g,
                                   (__attribute__((address_space(3))) void*)l, 16, 0, 0);
}

// ---- shared 128x128-tile NT GEMM core (BK=64, 4 waves, each 64x64) ----
__device__ __forceinline__ void gemm_tile(const ushort_t* A, const ushort_t* B,
                                          long lda, long ldb, int ksteps,
                                          ushort_t* lA, ushort_t* lB, f32x4 acc[4][4]) {
  const int tid = threadIdx.x;
  const int lane = tid & 63;
  const int wid = tid >> 6;
  const int wr = wid >> 1, wc = wid & 1;
  const int lrow = lane & 15;
  const int lk8 = (lane >> 4) * 8;

  for (int kt = 0; kt < ksteps; ++kt) {
    const ushort_t* Ak = A + (size_t)kt * 64;
    const ushort_t* Bk = B + (size_t)kt * 64;
#pragma unroll
    for (int r = 0; r < 4; ++r) {
      int slot = tid + r * 256;          // 0..1023, 16B each
      int row = slot >> 3;
      int col = (slot & 7) * 8;
      load16(Ak + (size_t)row * lda + col, lA + slot * 8);
      load16(Bk + (size_t)row * ldb + col, lB + slot * 8);
    }
    __syncthreads();   // compiler emits s_waitcnt vmcnt(0) before barrier
#pragma unroll
    for (int ks = 0; ks < 2; ++ks) {
      bf16x8 af[4], bb[4];
#pragma unroll
      for (int mi = 0; mi < 4; ++mi)
        af[mi] = *(const bf16x8*)(lA + ((wr * 64 + mi * 16 + lrow) * 64 + ks * 32 + lk8));
#pragma unroll
      for (int ni = 0; ni < 4; ++ni)
        bb[ni] = *(const bf16x8*)(lB + ((wc * 64 + ni * 16 + lrow) * 64 + ks * 32 + lk8));
#pragma unroll
      for (int mi = 0; mi < 4; ++mi)
#pragma unroll
        for (int ni = 0; ni < 4; ++ni)
          acc[mi][ni] = __builtin_amdgcn_mfma_f32_16x16x32_bf16(af[mi], bb[ni], acc[mi][ni], 0, 0, 0);
    }
    __syncthreads();
  }
}

// ---- prep: fp32 X -> bf16 Xb, cX = -0.5*||x||^2 - 0.5*ln(512) ----
__global__ __launch_bounds__(256) void k_prep_x(const float* __restrict__ X,
                                                ushort_t* __restrict__ Xb,
                                                float* __restrict__ cX) {
  int wid = threadIdx.x >> 6, lane = threadIdx.x & 63;
  size_t row = (size_t)blockIdx.x * 4 + wid;
  const float4* xr = (const float4*)(X + row * FEAT);
  float4 a = xr[lane], b = xr[lane + 64];
  float s = a.x * a.x + a.y * a.y + a.z * a.z + a.w * a.w
          + b.x * b.x + b.y * b.y + b.z * b.z + b.w * b.w;
#pragma unroll
  for (int off = 32; off; off >>= 1) s += __shfl_xor(s, off, 64);
  u16x4 pa = {f2b(a.x), f2b(a.y), f2b(a.z), f2b(a.w)};
  u16x4 pb = {f2b(b.x), f2b(b.y), f2b(b.z), f2b(b.w)};
  u16x4* xo = (u16x4*)(Xb + row * FEAT);
  xo[lane] = pa;
  xo[lane + 64] = pb;
  if (lane == 0) cX[row] = -0.5f * s - 3.11916231f;   // 0.5*ln(512)
}

__global__ __launch_bounds__(256) void k_prep_omega(const float* __restrict__ om,
                                                    ushort_t* __restrict__ Ob) {
  int i = blockIdx.x * 256 + threadIdx.x;   // 65536 float4 slots
  float4 v = ((const float4*)om)[i];
  u16x4 o = {f2b(v.x), f2b(v.y), f2b(v.z), f2b(v.w)};
  ((u16x4*)Ob)[i] = o;
}

// ---- V fp32 [n][512] -> VT bf16 [512][n] ----
__global__ __launch_bounds__(256) void k_vt(const float* __restrict__ V,
                                            ushort_t* __restrict__ VT) {
  __shared__ ushort_t t[64][72];
  int r0 = blockIdx.x * 64;   // node base
  int c0 = blockIdx.y * 64;   // feature(d) base
#pragma unroll
  for (int it = 0; it < 4; ++it) {
    int slot = threadIdx.x + it * 256;  // 0..1023
    int r = slot >> 4;
    int c4 = slot & 15;
    float4 v = *(const float4*)(V + (size_t)(r0 + r) * FEAT + c0 + c4 * 4);
    u16x4 p = {f2b(v.x), f2b(v.y), f2b(v.z), f2b(v.w)};
    *(u16x4*)&t[r][c4 * 4] = p;
  }
  __syncthreads();
#pragma unroll
  for (int it = 0; it < 2; ++it) {
    int slot = threadIdx.x + it * 256;  // 0..511
    int dr = slot >> 3;
    int n8 = slot & 7;
    u16x8 o;
#pragma unroll
    for (int j = 0; j < 8; ++j) o[j] = t[n8 * 8 + j][dr];
    *(u16x8*)(VT + (size_t)(c0 + dr) * N_NODES + r0 + n8 * 8) = o;
  }
}

// ---- phi GEMM: C = exp(Xb @ omega^T + cX) ; store row-major (Q) or transposed (K) ----
__global__ __launch_bounds__(256) void k_phi(const ushort_t* __restrict__ Xb,
                                             const ushort_t* __restrict__ Ob,
                                             const float* __restrict__ cX,
                                             ushort_t* __restrict__ Out, int transposed) {
  __shared__ ushort_t lA[128 * 64], lB[128 * 64];
  f32x4 acc[4][4];
#pragma unroll
  for (int i = 0; i < 4; ++i)
#pragma unroll
    for (int j = 0; j < 4; ++j) acc[i][j] = (f32x4){0.f, 0.f, 0.f, 0.f};
  const int m0 = blockIdx.y * 128, n0 = blockIdx.x * 128;
  gemm_tile(Xb + (size_t)m0 * FEAT, Ob + (size_t)n0 * FEAT, FEAT, FEAT, 8, lA, lB, acc);

  const int lane = threadIdx.x & 63, wid = threadIdx.x >> 6;
  const int wr = wid >> 1, wc = wid & 1;
  const int cbase = n0 + wc * 64 + (lane & 15);
  const int rbase = m0 + wr * 64 + ((lane >> 4) << 2);
#pragma unroll
  for (int mi = 0; mi < 4; ++mi) {
    int r0 = rbase + mi * 16;
    float cv[4];
#pragma unroll
    for (int j = 0; j < 4; ++j) cv[j] = cX[r0 + j];
#pragma unroll
    for (int ni = 0; ni < 4; ++ni) {
      int col = cbase + ni * 16;
      if (transposed) {
        u16x4 pk;
#pragma unroll
        for (int j = 0; j < 4; ++j) pk[j] = f2b(__expf(acc[mi][ni][j] + cv[j]));
        *(u16x4*)(Out + (size_t)col * N_NODES + r0) = pk;
      } else {
#pragma unroll
        for (int j = 0; j < 4; ++j)
          Out[(size_t)(r0 + j) * FEAT + col] = f2b(__expf(acc[mi][ni][j] + cv[j]));
      }
    }
  }
}

// ---- k_ones[feat] = row sums of K_hat^T ----
__global__ __launch_bounds__(256) void k_rowsum(const ushort_t* __restrict__ KT,
                                                float* __restrict__ k1) {
  const ushort_t* row = KT + (size_t)blockIdx.x * N_NODES;
  float s = 0.f;
  for (int i = threadIdx.x; i < N_NODES / 8; i += 256) {
    u16x8 v = ((const u16x8*)row)[i];
#pragma unroll
    for (int j = 0; j < 8; ++j) s += b2f(v[j]);
  }
#pragma unroll
  for (int off = 32; off; off >>= 1) s += __shfl_xor(s, off, 64);
  __shared__ float wsum[4];
  int lane = threadIdx.x & 63, wid = threadIdx.x >> 6;
  if (lane == 0) wsum[wid] = s;
  __syncthreads();
  if (threadIdx.x == 0) k1[blockIdx.x] = wsum[0] + wsum[1] + wsum[2] + wsum[3];
}

// ---- kv split-K GEMM: partials[z][feat][d] ----
__global__ __launch_bounds__(256) void k_kv(const ushort_t* __restrict__ KT,
                                            const ushort_t* __restrict__ VT,
                                            float* __restrict__ P) {
  __shared__ ushort_t lA[128 * 64], lB[128 * 64];
  f32x4 acc[4][4];
#pragma unroll
  for (int i = 0; i < 4; ++i)
#pragma unroll
    for (int j = 0; j < 4; ++j) acc[i][j] = (f32x4){0.f, 0.f, 0.f, 0.f};
  const int m0 = blockIdx.y * 128, n0 = blockIdx.x * 128, z = blockIdx.z;
  gemm_tile(KT + (size_t)m0 * N_NODES + z * 2048,
            VT + (size_t)n0 * N_NODES + z * 2048, N_NODES, N_NODES, 32, lA, lB, acc);
  float* Pz = P + (size_t)z * (FEAT * FEAT);
  const int lane = threadIdx.x & 63, wid = threadIdx.x >> 6;
  const int wr = wid >> 1, wc = wid & 1;
  const int cbase = n0 + wc * 64 + (lane & 15);
  const int rbase = m0 + wr * 64 + ((lane >> 4) << 2);
#pragma unroll
  for (int mi = 0; mi < 4; ++mi)
#pragma unroll
    for (int ni = 0; ni < 4; ++ni)
#pragma unroll
      for (int j = 0; j < 4; ++j)
        Pz[(size_t)(rbase + mi * 16 + j) * FEAT + cbase + ni * 16] = acc[mi][ni][j];
}

// ---- reduce partials -> kvT bf16 [d][feat] ----
__global__ __launch_bounds__(256) void k_redkv(const float* __restrict__ P,
                                               ushort_t* __restrict__ kvT) {
  int t = blockIdx.x * 256 + threadIdx.x;  // 0..65535
  int m = t >> 7;       // feat 0..511
  int d4 = t & 127;     // d/4
  float4 s = {0.f, 0.f, 0.f, 0.f};
  for (int z = 0; z < 32; ++z) {
    float4 v = *(const float4*)(P + (size_t)z * (FEAT * FEAT) + (size_t)m * FEAT + d4 * 4);
    s.x += v.x; s.y += v.y; s.z += v.z; s.w += v.w;
  }
  kvT[(size_t)(d4 * 4 + 0) * FEAT + m] = f2b(s.x);
  kvT[(size_t)(d4 * 4 + 1) * FEAT + m] = f2b(s.y);
  kvT[(size_t)(d4 * 4 + 2) * FEAT + m] = f2b(s.z);
  kvT[(size_t)(d4 * 4 + 3) * FEAT + m] = f2b(s.w);
}

// ---- d_diag = Q_hat @ k_ones ----
__global__ __launch_bounds__(256) void k_dd(const ushort_t* __restrict__ Qh,
                                            const float* __restrict__ k1,
                                            float* __restrict__ dd) {
  int rid = threadIdx.x >> 4, l16 = threadIdx.x & 15;
  int row = blockIdx.x * 16 + rid;
  const ushort_t* qr = Qh + (size_t)row * FEAT;
  float s = 0.f;
#pragma unroll
  for (int it = 0; it < 4; ++it) {
    int cb = it * 128 + l16 * 8;
    u16x8 q = *(const u16x8*)(qr + cb);
    float4 ka = *(const float4*)(k1 + cb);
    float4 kb = *(const float4*)(k1 + cb + 4);
    s += b2f(q[0]) * ka.x + b2f(q[1]) * ka.y + b2f(q[2]) * ka.z + b2f(q[3]) * ka.w
       + b2f(q[4]) * kb.x + b2f(q[5]) * kb.y + b2f(q[6]) * kb.z + b2f(q[7]) * kb.w;
  }
  s += __shfl_xor(s, 1, 64); s += __shfl_xor(s, 2, 64);
  s += __shfl_xor(s, 4, 64); s += __shfl_xor(s, 8, 64);
  if (l16 == 0) dd[row] = s;
}

// ---- final GEMM: out = (Q_hat @ kv) / d_diag ----
__global__ __launch_bounds__(256) void k_final(const ushort_t* __restrict__ Qh,
                                               const ushort_t* __restrict__ kvT,
                                               const float* __restrict__ dd,
                                               float* __restrict__ out) {
  __shared__ ushort_t lA[128 * 64], lB[128 * 64];
  f32x4 acc[4][4];
#pragma unroll
  for (int i = 0; i < 4; ++i)
#pragma unroll
    for (int j = 0; j < 4; ++j) acc[i][j] = (f32x4){0.f, 0.f, 0.f, 0.f};
  const int m0 = blockIdx.y * 128, n0 = blockIdx.x * 128;
  gemm_tile(Qh + (size_t)m0 * FEAT, kvT + (size_t)n0 * FEAT, FEAT, FEAT, 8, lA, lB, acc);
  const int lane = threadIdx.x & 63, wid = threadIdx.x >> 6;
  const int wr = wid >> 1, wc = wid & 1;
  const int cbase = n0 + wc * 64 + (lane & 15);
  const int rbase = m0 + wr * 64 + ((lane >> 4) << 2);
#pragma unroll
  for (int mi = 0; mi < 4; ++mi) {
    int r0 = rbase + mi * 16;
    float inv[4];
#pragma unroll
    for (int j = 0; j < 4; ++j) inv[j] = 1.0f / dd[r0 + j];
#pragma unroll
    for (int ni = 0; ni < 4; ++ni) {
      int col = cbase + ni * 16;
#pragma unroll
      for (int j = 0; j < 4; ++j)
        out[(size_t)(r0 + j) * FEAT + col] = acc[mi][ni][j] * inv[j];
    }
  }
}

extern "C" void kernel_launch(void* const* d_in, const int* in_sizes, int n_in,
                              void* d_out, int out_size, void* d_ws, size_t ws_size,
                              hipStream_t stream) {
  const float* Q = (const float*)d_in[0];
  const float* K = (const float*)d_in[1];
  const float* V = (const float*)d_in[2];
  const float* omega = (const float*)d_in[3];
  float* out = (float*)d_out;

  char* ws = (char*)d_ws;
  ushort_t* B1  = (ushort_t*)(ws);                  // 64 MB: Kb -> VT -> Qb
  ushort_t* B2  = (ushort_t*)(ws + 67108864);       // 64 MB: K_hat^T -> Q_hat
  ushort_t* Ob  = (ushort_t*)(ws + 134217728);      // 512 KB omega bf16
  ushort_t* kvT = (ushort_t*)(ws + 134742016);      // 512 KB kv^T bf16
  float*    k1  = (float*)(ws + 135266304);         // 2 KB k_ones
  float*    cX  = (float*)(ws + 135268352);         // 256 KB cX
  float*    dd  = (float*)(ws + 135530496);         // 256 KB d_diag
  // split-K partials (32 MB) aliased into d_out: fully consumed by k_redkv
  // before k_final overwrites d_out (stream-ordered).
  float*    P   = (float*)d_out;

  k_prep_x<<<N_NODES / 4, 256, 0, stream>>>(K, B1, cX);
  k_prep_omega<<<256, 256, 0, stream>>>(omega, Ob);
  k_phi<<<dim3(4, 512), 256, 0, stream>>>(B1, Ob, cX, B2, 1);   // -> K_hat^T
  k_rowsum<<<512, 256, 0, stream>>>(B2, k1);
  k_vt<<<dim3(N_NODES / 64, 8), 256, 0, stream>>>(V, B1);       // -> V^T
  k_kv<<<dim3(4, 4, 32), 256, 0, stream>>>(B2, B1, P);
  k_prep_x<<<N_NODES / 4, 256, 0, stream>>>(Q, B1, cX);
  k_phi<<<dim3(4, 512), 256, 0, stream>>>(B1, Ob, cX, B2, 0);   // -> Q_hat
  k_redkv<<<256, 256, 0, stream>>>(P, kvT);
  k_dd<<<N_NODES / 16, 256, 0, stream>>>(B2, k1, dd);
  k_final<<<dim3(4, 512), 256, 0, stream>>>(B2, kvT, dd, out);
}